// Round 14
// baseline (75.754 us; speedup 1.0000x reference)
//
#include <hip/hip_runtime.h>

#define NB 2
#define NH 16
#define SEQ 4096
#define HD 64
#define DIM 1024
#define WIN 512

typedef float f32x4h __attribute__((ext_vector_type(4)));
typedef short bf16x8 __attribute__((ext_vector_type(8)));
typedef unsigned int u32x4 __attribute__((ext_vector_type(4)));
typedef unsigned short u16;
typedef unsigned int u32;

__device__ __forceinline__ u16 f2bf(float x) {
    u32 u = __float_as_uint(x);
    u += 0x7FFFu + ((u >> 16) & 1u);
    return (u16)(u >> 16);
}

// pack 2 f32 -> 1 u32 of 2 bf16 (RNE) in one VALU op
__device__ __forceinline__ u32 cvtpk(float lo, float hi) {
    u32 r;
    asm("v_cvt_pk_bf16_f32 %0, %1, %2" : "=v"(r) : "v"(lo), "v"(hi));
    return r;
}

// cubic 2^x for |x| <= 0.28 (l2-norm bounds scores): rel err < 6e-5, main VALU pipe
__device__ __forceinline__ float pexp2(float x) {
    return 1.f + x * (0.69314718f + x * (0.24022651f + x * 0.05550411f));
}

// ---------------- trig table ----------------
__global__ void trig_kernel(float* __restrict__ ct, float* __restrict__ st) {
    int idx = blockIdx.x * 256 + threadIdx.x;   // 4096*32
    int s = idx >> 5, j = idx & 31;
    float inv = powf(1.0f / 10000.0f, (float)j * (1.0f / 32.0f));
    float ang = (float)s * inv;
    ct[idx] = cosf(ang);
    st[idx] = sinf(ang);
}

// ---------------- k: l2-normalize + rope -> bf16, head-major ----------------
__device__ __forceinline__ void norm_rope_row(const float* __restrict__ row,
                                              const float* __restrict__ cr,
                                              const float* __restrict__ sr,
                                              float scale, u16* __restrict__ dst, int a) {
    float4 u0 = *(const float4*)(row + 8 * a);
    float4 u1 = *(const float4*)(row + 8 * a + 4);
    float4 v0 = *(const float4*)(row + 32 + 8 * a);
    float4 v1 = *(const float4*)(row + 32 + 8 * a + 4);
    float x1[8] = {u0.x, u0.y, u0.z, u0.w, u1.x, u1.y, u1.z, u1.w};
    float x2[8] = {v0.x, v0.y, v0.z, v0.w, v1.x, v1.y, v1.z, v1.w};
    float ss = 0.f;
#pragma unroll
    for (int i = 0; i < 8; ++i) ss += x1[i] * x1[i] + x2[i] * x2[i];
    ss += __shfl_xor(ss, 1);
    ss += __shfl_xor(ss, 2);
    float rn = scale / fmaxf(sqrtf(ss), 1e-6f);
    u16 o1[8], o2[8];
#pragma unroll
    for (int i = 0; i < 8; ++i) {
        float c = cr[8 * a + i], sn = sr[8 * a + i];
        o1[i] = f2bf((x1[i] * c + x2[i] * sn) * rn);
        o2[i] = f2bf((x2[i] * c - x1[i] * sn) * rn);
    }
    uint4 w1, w2;
    w1.x = (u32)o1[0] | ((u32)o1[1] << 16); w1.y = (u32)o1[2] | ((u32)o1[3] << 16);
    w1.z = (u32)o1[4] | ((u32)o1[5] << 16); w1.w = (u32)o1[6] | ((u32)o1[7] << 16);
    w2.x = (u32)o2[0] | ((u32)o2[1] << 16); w2.y = (u32)o2[2] | ((u32)o2[3] << 16);
    w2.z = (u32)o2[4] | ((u32)o2[5] << 16); w2.w = (u32)o2[6] | ((u32)o2[7] << 16);
    *(uint4*)(dst + 8 * a) = w1;
    *(uint4*)(dst + 32 + 8 * a) = w2;
}

__global__ void k_prep(const float* __restrict__ xk,
                       const float* __restrict__ ctab, const float* __restrict__ stab,
                       u16* __restrict__ Kn) {
    int bid = blockIdx.x;             // 2048 = 32 bh * 64 s-tiles
    int bh = bid >> 6, stile = bid & 63;
    int b = bh >> 4, h = bh & 15;
    int t = threadIdx.x;
    int lr = t >> 2, a = t & 3;
    int s = stile * 64 + lr;
    size_t inoff = ((size_t)(b * SEQ + s)) * DIM + h * HD;
    size_t outoff = ((size_t)bh * SEQ + s) * HD;
    norm_rope_row(xk + inoff, ctab + (size_t)s * 32, stab + (size_t)s * 32, 1.0f, Kn + outoff, a);
}

// ---------------- v: bf16 + transpose to Vt[bh][dim][s] ----------------
__global__ void v_prep(const float* __restrict__ xv, u16* __restrict__ Vt) {
    __shared__ u16 tile[64][66];
    int bid = blockIdx.x;
    int bh = bid >> 6, stile = bid & 63;
    int b = bh >> 4, h = bh & 15;
    int t = threadIdx.x;
    int lr = t >> 2, a = t & 3;
    int s = stile * 64 + lr;
    const float* vrow = xv + ((size_t)(b * SEQ + s)) * DIM + h * HD + 16 * a;
#pragma unroll
    for (int c = 0; c < 4; ++c) {
        float4 w = *(const float4*)(vrow + 4 * c);
        tile[lr][16 * a + 4 * c + 0] = f2bf(w.x);
        tile[lr][16 * a + 4 * c + 1] = f2bf(w.y);
        tile[lr][16 * a + 4 * c + 2] = f2bf(w.z);
        tile[lr][16 * a + 4 * c + 3] = f2bf(w.w);
    }
    __syncthreads();
    int d = t >> 2;
    u32 pk[8];
#pragma unroll
    for (int i = 0; i < 8; ++i) {
        u16 lo = tile[16 * a + 2 * i][d];
        u16 hi = tile[16 * a + 2 * i + 1][d];
        pk[i] = (u32)lo | ((u32)hi << 16);
    }
    u16* dst = Vt + ((size_t)bh * HD + d) * SEQ + stile * 64 + 16 * a;
    *(uint4*)(dst) = make_uint4(pk[0], pk[1], pk[2], pk[3]);
    *(uint4*)(dst + 8) = make_uint4(pk[4], pk[5], pk[6], pk[7]);
}

// ---------------- attention: 16x16x32 MFMA, 16 q-rows/wave (half register state ->
//                  ~2x occupancy), fixed-shift softmax, LDS-staged KV (r10 staging) ----------------
// grid = 32 bh * 64 q-tiles(64 rows) = 2048 blocks; 4 waves/block, each wave 16 q-rows.
#define KROW 72   // u16 stride per K row (144B)
#define VROW 40   // u16 stride per V row (80B)
__global__ __launch_bounds__(256, 5) void attn_kernel(const float* __restrict__ xq,
                                                      const u16* __restrict__ Kn,
                                                      const u16* __restrict__ Vt,
                                                      const float* __restrict__ ctab,
                                                      const float* __restrict__ stab,
                                                      float* __restrict__ out) {
    __shared__ __align__(16) u16 Kl[2][32 * KROW];   //  9216 B
    __shared__ __align__(16) u16 Vl[2][64 * VROW];   // 10240 B
    int phys = blockIdx.x;
    int logical = (phys & 7) * 256 + (phys >> 3);   // bijective: 2048 = 8 * 256
    int bh = logical >> 6, qt = logical & 63;
    int b = bh >> 4, h = bh & 15;
    int tid = threadIdx.x;
    int w = tid >> 6, l = tid & 63;
    int q16 = l & 15, g = l >> 4;                   // col q, k-group
    int qblk = qt * 64;
    int qw0 = qblk + w * 16;
    int dq = qw0 + q16;
    const u16* Kh = Kn + (size_t)bh * SEQ * HD;
    const u16* Vh = Vt + (size_t)bh * HD * SEQ;

    // ---- fused Q prep: lane g covers dims {g*8..+7} (x1) and {32+g*8..+7} (x2) — a
    // complete RoPE pair set, so rotation is lane-local. Norm reduce across g-groups.
    const float* qrow = xq + ((size_t)(b * SEQ + dq)) * DIM + h * HD;
    float4 xA = *(const float4*)(qrow + g * 8);
    float4 xB = *(const float4*)(qrow + g * 8 + 4);
    float4 yA = *(const float4*)(qrow + 32 + g * 8);
    float4 yB = *(const float4*)(qrow + 36 + g * 8);
    auto d4 = [](float4 v) { return v.x * v.x + v.y * v.y + v.z * v.z + v.w * v.w; };
    float ss = d4(xA) + d4(xB) + d4(yA) + d4(yB);
    ss += __shfl_xor(ss, 16);
    ss += __shfl_xor(ss, 32);
    float rn = (0.125f * 1.44269504f) / fmaxf(sqrtf(ss), 1e-6f);   // fold scale*log2e
    const float* crp = ctab + (size_t)dq * 32 + g * 8;
    const float* srp = stab + (size_t)dq * 32 + g * 8;
    float4 cA = *(const float4*)(crp);
    float4 cB = *(const float4*)(crp + 4);
    float4 sA = *(const float4*)(srp);
    float4 sB = *(const float4*)(srp + 4);
    u32x4 r1, r2;
    r1[0] = cvtpk((xA.x * cA.x + yA.x * sA.x) * rn, (xA.y * cA.y + yA.y * sA.y) * rn);
    r1[1] = cvtpk((xA.z * cA.z + yA.z * sA.z) * rn, (xA.w * cA.w + yA.w * sA.w) * rn);
    r1[2] = cvtpk((xB.x * cB.x + yB.x * sB.x) * rn, (xB.y * cB.y + yB.y * sB.y) * rn);
    r1[3] = cvtpk((xB.z * cB.z + yB.z * sB.z) * rn, (xB.w * cB.w + yB.w * sB.w) * rn);
    r2[0] = cvtpk((yA.x * cA.x - xA.x * sA.x) * rn, (yA.y * cA.y - xA.y * sA.y) * rn);
    r2[1] = cvtpk((yA.z * cA.z - xA.z * sA.z) * rn, (yA.w * cA.w - xA.w * sA.w) * rn);
    r2[2] = cvtpk((yB.x * cB.x - xB.x * sB.x) * rn, (yB.y * cB.y - xB.y * sB.y) * rn);
    r2[3] = cvtpk((yB.z * cB.z - xB.z * sB.z) * rn, (yB.w * cB.w - xB.w * sB.w) * rn);
    bf16x8 qf0 = __builtin_bit_cast(bf16x8, r1);   // dims g*8..+7   (k-slots, MFMA 1)
    bf16x8 qf1 = __builtin_bit_cast(bf16x8, r2);   // dims 32+g*8..+7 (MFMA 2)

    f32x4h acc0 = {0,0,0,0}, acc1 = {0,0,0,0}, acc2 = {0,0,0,0}, acc3 = {0,0,0,0};
    float l_ = 0.f;

    int tw0 = (qw0 - (WIN - 1)) >> 5; if (tw0 < 0) tw0 = 0;
    int tw1 = (qw0 + 15) >> 5;
    int bt0 = (qblk - (WIN - 1)) >> 5; if (bt0 < 0) bt0 = 0;
    int bt1 = (qblk + 63) >> 5;

    // staging assignments (per thread, constant across tiles) — same as r10/r13
    int krow = tid >> 3, kc = (tid & 7) * 8;        // K: 32 rows x 8 chunks of 8 u16
    int vrw  = tid >> 2, vc = (tid & 3) * 8;        // V: 64 rows x 4 chunks of 8 u16
    const u16* kgl = Kh + (size_t)krow * HD + kc;
    const u16* vgl = Vh + (size_t)vrw * SEQ + vc;
    u16* kls0 = &Kl[0][krow * KROW + kc];
    u16* kls1 = &Kl[1][krow * KROW + kc];
    u16* vls0 = &Vl[0][vrw * VROW + vc];
    u16* vls1 = &Vl[1][vrw * VROW + vc];

    // prologue: stage tile bt0 into buffer 0
    {
        uint4 gk = *(const uint4*)(kgl + ((size_t)bt0 << 5) * HD);
        uint4 gv = *(const uint4*)(vgl + (bt0 << 5));
        *(uint4*)kls0 = gk;
        *(uint4*)vls0 = gv;
    }
    __syncthreads();

    int c = 0;
    for (int t = bt0; t <= bt1; ++t) {
        int kv0 = t << 5;
        bool more = t < bt1;
        uint4 gk, gv;
        if (more) {
            gk = *(const uint4*)(kgl + ((size_t)(kv0 + 32)) * HD);
            gv = *(const uint4*)(vgl + (kv0 + 32));
        }

        if (t >= tw0 && t <= tw1) {
            bool mask = (t == tw0) || (t == tw1);
            const u16* Kb = c ? &Kl[1][0] : &Kl[0][0];
            const u16* Vb = c ? &Vl[1][0] : &Vl[0][0];

            // --- QK^T (swapped): S^T[32 keys][16 q] as two 16x16 tiles ---
            const u16* kb = Kb + q16 * KROW;        // A-frag row = key = lane&15
            bf16x8 ka00 = *(const bf16x8*)(kb + g * 8);
            bf16x8 ka01 = *(const bf16x8*)(kb + 32 + g * 8);
            bf16x8 ka10 = *(const bf16x8*)(kb + 16 * KROW + g * 8);
            bf16x8 ka11 = *(const bf16x8*)(kb + 16 * KROW + 32 + g * 8);
            f32x4h st0 = {0,0,0,0}, st1 = {0,0,0,0};
            st0 = __builtin_amdgcn_mfma_f32_16x16x32_bf16(ka00, qf0, st0, 0, 0, 0);
            st0 = __builtin_amdgcn_mfma_f32_16x16x32_bf16(ka01, qf1, st0, 0, 0, 0);
            st1 = __builtin_amdgcn_mfma_f32_16x16x32_bf16(ka10, qf0, st1, 0, 0, 0);
            st1 = __builtin_amdgcn_mfma_f32_16x16x32_bf16(ka11, qf1, st1, 0, 0, 0);

            // V A-frags (row = dim, k = keys g*8..+7)
            bf16x8 v0 = *(const bf16x8*)(Vb + (q16) * VROW + g * 8);
            bf16x8 v1 = *(const bf16x8*)(Vb + (16 + q16) * VROW + g * 8);
            bf16x8 v2 = *(const bf16x8*)(Vb + (32 + q16) * VROW + g * 8);
            bf16x8 v3 = *(const bf16x8*)(Vb + (48 + q16) * VROW + g * 8);

            // --- softmax (fixed shift): C layout row = g*4 + r -> key = kv0 + [16kg] + g*4 + r
            int base0 = dq - (kv0 + g * 4);
            int base1 = base0 - 16;
            float e0 = pexp2(st0[0]), e1 = pexp2(st0[1]), e2 = pexp2(st0[2]), e3 = pexp2(st0[3]);
            float f0 = pexp2(st1[0]), f1 = pexp2(st1[1]), f2 = pexp2(st1[2]), f3 = pexp2(st1[3]);
            if (mask) {
                e0 = ((u32)(base0 - 0) < (u32)WIN) ? e0 : 0.f;
                e1 = ((u32)(base0 - 1) < (u32)WIN) ? e1 : 0.f;
                e2 = ((u32)(base0 - 2) < (u32)WIN) ? e2 : 0.f;
                e3 = ((u32)(base0 - 3) < (u32)WIN) ? e3 : 0.f;
                f0 = ((u32)(base1 - 0) < (u32)WIN) ? f0 : 0.f;
                f1 = ((u32)(base1 - 1) < (u32)WIN) ? f1 : 0.f;
                f2 = ((u32)(base1 - 2) < (u32)WIN) ? f2 : 0.f;
                f3 = ((u32)(base1 - 3) < (u32)WIN) ? f3 : 0.f;
            }
            l_ += ((e0 + e1) + (e2 + e3)) + ((f0 + f1) + (f2 + f3));

            // --- C -> B exchange: B word w_j = keys g*8 + {2j,2j+1} ---
            u32 pk0 = cvtpk(e0, e1), pk1 = cvtpk(e2, e3);   // keys g*4+{0,1},{2,3}
            u32 pk2 = cvtpk(f0, f1), pk3 = cvtpk(f2, f3);   // keys 16+g*4+{0,1},{2,3}
            u32 s16a = (g & 1) ? pk0 : pk2, s16b = (g & 1) ? pk1 : pk3;
            u32 sa   = (g & 2) ? pk0 : pk2, sb   = (g & 2) ? pk1 : pk3;
            u32 x16_0 = __shfl_xor(s16a, 16), x16_1 = __shfl_xor(s16b, 16);
            u32 x32_0 = __shfl_xor(sa, 32),   x32_1 = __shfl_xor(sb, 32);
            u32 x48_0 = __shfl_xor(sa, 48),   x48_1 = __shfl_xor(sb, 48);
            u32 w0 = (g == 0) ? pk0 : (g == 1) ? x48_0 : (g == 2) ? x32_0 : x16_0;
            u32 w1 = (g == 0) ? pk1 : (g == 1) ? x48_1 : (g == 2) ? x32_1 : x16_1;
            u32 w2 = (g == 0) ? x16_0 : (g == 1) ? x32_0 : (g == 2) ? x48_0 : pk2;
            u32 w3 = (g == 0) ? x16_1 : (g == 1) ? x32_1 : (g == 2) ? x48_1 : pk3;
            bf16x8 pb = __builtin_bit_cast(bf16x8, (u32x4){w0, w1, w2, w3});

            // --- PV (swapped): O^T[dim][q] += V^T P^T, 4 dim-groups ---
            acc0 = __builtin_amdgcn_mfma_f32_16x16x32_bf16(v0, pb, acc0, 0, 0, 0);
            acc1 = __builtin_amdgcn_mfma_f32_16x16x32_bf16(v1, pb, acc1, 0, 0, 0);
            acc2 = __builtin_amdgcn_mfma_f32_16x16x32_bf16(v2, pb, acc2, 0, 0, 0);
            acc3 = __builtin_amdgcn_mfma_f32_16x16x32_bf16(v3, pb, acc3, 0, 0, 0);
        }

        if (more) {
            *(uint4*)(c ? kls0 : kls1) = gk;
            *(uint4*)(c ? vls0 : vls1) = gv;
        }
        __syncthreads();
        c ^= 1;
    }

    l_ += __shfl_xor(l_, 16);
    l_ += __shfl_xor(l_, 32);
    float inv = 1.0f / l_;
    // O^T C layout: col = q (lane&15), row = dim = dg*16 + g*4 + r
    float* orow = out + ((size_t)(b * SEQ + dq)) * DIM + h * HD + g * 4;
    float4 o0 = { acc0[0] * inv, acc0[1] * inv, acc0[2] * inv, acc0[3] * inv };
    float4 o1 = { acc1[0] * inv, acc1[1] * inv, acc1[2] * inv, acc1[3] * inv };
    float4 o2 = { acc2[0] * inv, acc2[1] * inv, acc2[2] * inv, acc2[3] * inv };
    float4 o3 = { acc3[0] * inv, acc3[1] * inv, acc3[2] * inv, acc3[3] * inv };
    *(float4*)(orow + 0)  = o0;
    *(float4*)(orow + 16) = o1;
    *(float4*)(orow + 32) = o2;
    *(float4*)(orow + 48) = o3;
}

extern "C" void kernel_launch(void* const* d_in, const int* in_sizes, int n_in,
                              void* d_out, int out_size, void* d_ws, size_t ws_size,
                              hipStream_t stream) {
    (void)in_sizes; (void)n_in; (void)out_size; (void)ws_size;
    const float* xq = (const float*)d_in[0];
    const float* xk = (const float*)d_in[1];
    const float* xv = (const float*)d_in[2];
    float* out = (float*)d_out;

    const size_t HEADS_ELEMS = (size_t)NB * NH * SEQ * HD;   // 8,388,608
    u16* Kn = (u16*)d_ws;
    u16* Vt = Kn + HEADS_ELEMS;
    float* ctab = (float*)(Vt + HEADS_ELEMS);
    float* stab = ctab + (size_t)SEQ * 32;

    trig_kernel<<<dim3(512), dim3(256), 0, stream>>>(ctab, stab);
    k_prep<<<dim3(2048), dim3(256), 0, stream>>>(xk, ctab, stab, Kn);
    v_prep<<<dim3(2048), dim3(256), 0, stream>>>(xv, Vt);
    attn_kernel<<<dim3(2048), dim3(256), 0, stream>>>(xq, Kn, Vt, ctab, stab, out);
}